// Round 2
// baseline (7424.677 us; speedup 1.0000x reference)
//
#include <hip/hip_runtime.h>
#include <cstdint>
#include <cstddef>

#define DEVI __device__ __forceinline__

namespace {

constexpr int Bsz  = 16384;
constexpr int KIN  = 256;
constexpr int KST  = 1024;
constexpr int KOUT = 256;

// ---------------- fp32 NT GEMM core: C[M,N] = A[M,K] @ W[N,K]^T ----------------
// 128x128 tile, BK=16, 256 threads, 8x8 microtile per thread.
constexpr int BM = 128, BN = 128, BK = 16;
constexpr int LDT = BM + 4;   // +4 pad: keeps 16B alignment, spreads banks

DEVI float sigmoidf_(float x) { return 1.0f / (1.0f + expf(-x)); }

// ---------------- epilogues (row index r is LOCAL to the chunk) ----------------
struct EpTanhBias {            // out = tanh(v + bias[c])
    float* out; const float* bias; int ldo;
    DEVI void begin() {}
    DEVI void store(float v, int r, int c) { out[(size_t)r * ldo + c] = tanhf(v + bias[c]); }
};
struct EpPlain {               // out = v
    float* out; int ldo;
    DEVI void begin() {}
    DEVI void store(float v, int r, int c) { out[(size_t)r * ldo + c] = v; }
};
struct EpTanh {                // out = tanh(v)
    float* out; int ldo;
    DEVI void begin() {}
    DEVI void store(float v, int r, int c) { out[(size_t)r * ldo + c] = tanhf(v); }
};
struct EpGates {               // g = sigmoid(lx[r,c] + v + b_hg[c]); Z or RH=g*h
    float* Z; float* RH; const float* lx; const float* bhg; const float* h;
    DEVI void begin() {}
    DEVI void store(float v, int r, int c) {
        const float g = sigmoidf_(lx[(size_t)r * (3 * KST) + c] + v + bhg[c]);
        if (c < KST) {
            Z[(size_t)r * KST + c] = g;
        } else {
            const size_t i = (size_t)r * KST + (c - KST);
            RH[i] = g * h[i];
        }
    }
};
// lin = lx[r, 2K+c] + v + b_hl[c]; k = Z*(tanh(lin) - h); RK4 stage update.
// STAGE 0: acc=k,            hnext = state + 0.5*dt*k
// STAGE 1: acc+=2k,          hnext = state + 0.5*dt*k   (h/hnext same buffer, in-place OK:
//                                                        each index owned by one thread)
// STAGE 2: acc+=2k,          hnext = state + dt*k
// STAGE 3: acc = state + dt*(acc+k)/6   (acc buffer IS state_new output slice)
template <int STAGE>
struct EpLin {
    const float* Z; const float* lx; const float* bhl; const float* h;
    const float* state; float* acc; float* hnext; const float* dtp;
    float dtv;
    DEVI void begin() { dtv = *dtp; }
    DEVI void store(float v, int r, int c) {
        const size_t i = (size_t)r * KST + c;
        const float lin = lx[(size_t)r * (3 * KST) + 2 * KST + c] + v + bhl[c];
        const float k = Z[i] * (tanhf(lin) - h[i]);   // MEANDT == 1
        if constexpr (STAGE == 0) { acc[i] = k;             hnext[i] = state[i] + 0.5f * dtv * k; }
        else if constexpr (STAGE == 1) { acc[i] += 2.f * k; hnext[i] = state[i] + 0.5f * dtv * k; }
        else if constexpr (STAGE == 2) { acc[i] += 2.f * k; hnext[i] = state[i] + dtv * k; }
        else { acc[i] = state[i] + dtv * (acc[i] + k) * (1.f / 6.f); }
    }
};

template <class Ep>
__global__ __launch_bounds__(256)
void gemm_nt(const float* __restrict__ A, const float* __restrict__ W,
             const int K, Ep ep)
{
    __shared__ float As[BK][LDT];
    __shared__ float Bs[BK][LDT];
    const int m0 = blockIdx.x * BM;
    const int n0 = blockIdx.y * BN;
    const int tid = threadIdx.x;
    const int tx = tid & 15;        // 0..15 -> N microtile
    const int ty = tid >> 4;        // 0..15 -> M microtile
    const int lr = tid >> 2;        // 0..63  loader row
    const int lc = (tid & 3) << 2;  // 0,4,8,12 loader k-col

    const float* Ap = A + (size_t)(m0 + lr) * K + lc;
    const float* Wp = W + (size_t)(n0 + lr) * K + lc;

    float acc[8][8];
#pragma unroll
    for (int i = 0; i < 8; ++i)
#pragma unroll
        for (int j = 0; j < 8; ++j) acc[i][j] = 0.f;

    for (int k0 = 0; k0 < K; k0 += BK) {
        const float4 a0 = *reinterpret_cast<const float4*>(Ap + k0);
        const float4 a1 = *reinterpret_cast<const float4*>(Ap + (size_t)64 * K + k0);
        const float4 b0 = *reinterpret_cast<const float4*>(Wp + k0);
        const float4 b1 = *reinterpret_cast<const float4*>(Wp + (size_t)64 * K + k0);
        __syncthreads();
        As[lc + 0][lr] = a0.x; As[lc + 1][lr] = a0.y; As[lc + 2][lr] = a0.z; As[lc + 3][lr] = a0.w;
        As[lc + 0][lr + 64] = a1.x; As[lc + 1][lr + 64] = a1.y; As[lc + 2][lr + 64] = a1.z; As[lc + 3][lr + 64] = a1.w;
        Bs[lc + 0][lr] = b0.x; Bs[lc + 1][lr] = b0.y; Bs[lc + 2][lr] = b0.z; Bs[lc + 3][lr] = b0.w;
        Bs[lc + 0][lr + 64] = b1.x; Bs[lc + 1][lr + 64] = b1.y; Bs[lc + 2][lr + 64] = b1.z; Bs[lc + 3][lr + 64] = b1.w;
        __syncthreads();
#pragma unroll
        for (int kk = 0; kk < BK; ++kk) {
            const float4 af0 = *reinterpret_cast<const float4*>(&As[kk][ty * 4]);
            const float4 af1 = *reinterpret_cast<const float4*>(&As[kk][64 + ty * 4]);
            const float4 bf0 = *reinterpret_cast<const float4*>(&Bs[kk][tx * 4]);
            const float4 bf1 = *reinterpret_cast<const float4*>(&Bs[kk][64 + tx * 4]);
            const float a[8] = {af0.x, af0.y, af0.z, af0.w, af1.x, af1.y, af1.z, af1.w};
            const float b[8] = {bf0.x, bf0.y, bf0.z, bf0.w, bf1.x, bf1.y, bf1.z, bf1.w};
#pragma unroll
            for (int i = 0; i < 8; ++i)
#pragma unroll
                for (int j = 0; j < 8; ++j)
                    acc[i][j] = fmaf(a[i], b[j], acc[i][j]);
        }
    }

    ep.begin();
#pragma unroll
    for (int i = 0; i < 8; ++i) {
        const int r = m0 + ((i < 4) ? (ty * 4 + i) : (64 + ty * 4 + (i - 4)));
#pragma unroll
        for (int j = 0; j < 8; ++j) {
            const int c = n0 + ((j < 4) ? (tx * 4 + j) : (64 + tx * 4 + (j - 4)));
            ep.store(acc[i][j], r, c);
        }
    }
}

} // namespace

extern "C" void kernel_launch(void* const* d_in, const int* in_sizes, int n_in,
                              void* d_out, int out_size, void* d_ws, size_t ws_size,
                              hipStream_t stream)
{
    (void)in_sizes; (void)n_in; (void)out_size;

    const float* x     = (const float*)d_in[0];
    const float* state = (const float*)d_in[1];
    const float* dtp   = (const float*)d_in[2];
    const float* W_in  = (const float*)d_in[3];
    const float* b_in  = (const float*)d_in[4];
    const float* W_lx  = (const float*)d_in[5];
    const float* W_hg  = (const float*)d_in[6];
    const float* b_hg  = (const float*)d_in[7];
    const float* W_hl  = (const float*)d_in[8];
    const float* b_hl  = (const float*)d_in[9];
    const float* W_y1  = (const float*)d_in[10];
    const float* W_y2  = (const float*)d_in[11];

    float* y_out  = (float*)d_out;                    // [B, KOUT]
    float* st_new = y_out + (size_t)Bsz * KOUT;       // [B, KST]; doubles as RK4 acc

    // Chunked over batch: per-chunk ws = 6*CB*KST floats
    //   x0h (CB*K: x0, then h) | lx (CB*3K) | Z (CB*K) | RH (CB*K)
    // CB chosen from ws_size (constant across calls -> graph-safe).
    int CB = 1024;
    while (CB < Bsz && (size_t)(CB * 2) * KST * 6 * sizeof(float) <= ws_size) CB <<= 1;
    if ((size_t)CB * KST * 6 * sizeof(float) > ws_size) return;  // <24MB scratch: give up

    float* x0h = (float*)d_ws;                 // CB*K
    float* lx  = x0h + (size_t)CB * KST;       // CB*3K
    float* Zb  = lx + (size_t)CB * 3 * KST;    // CB*K
    float* RH  = Zb + (size_t)CB * KST;        // CB*K

    const dim3 blk(256);
    auto grid = [](int M, int N) { return dim3((unsigned)(M / BM), (unsigned)(N / BN)); };

    for (int c0 = 0; c0 < Bsz; c0 += CB) {
        const float* xs = x + (size_t)c0 * KIN;
        const float* ss = state + (size_t)c0 * KST;
        float* sn = st_new + (size_t)c0 * KST;

        // 1) x0 = tanh(x @ W_in^T + b_in)
        gemm_nt<<<grid(CB, KST), blk, 0, stream>>>(xs, W_in, KIN, EpTanhBias{x0h, b_in, KST});
        // 2) lx = x0 @ W_lx^T   (hoisted: depends only on x0)
        gemm_nt<<<grid(CB, 3 * KST), blk, 0, stream>>>(x0h, W_lx, KST, EpPlain{lx, 3 * KST});

        // 3) RK4 stages. After lx, x0 is dead; x0h becomes the h buffer.
        gemm_nt<<<grid(CB, 2 * KST), blk, 0, stream>>>(ss, W_hg, KST, EpGates{Zb, RH, lx, b_hg, ss});
        gemm_nt<<<grid(CB, KST), blk, 0, stream>>>(RH, W_hl, KST, EpLin<0>{Zb, lx, b_hl, ss, ss, sn, x0h, dtp});

        gemm_nt<<<grid(CB, 2 * KST), blk, 0, stream>>>(x0h, W_hg, KST, EpGates{Zb, RH, lx, b_hg, x0h});
        gemm_nt<<<grid(CB, KST), blk, 0, stream>>>(RH, W_hl, KST, EpLin<1>{Zb, lx, b_hl, x0h, ss, sn, x0h, dtp});

        gemm_nt<<<grid(CB, 2 * KST), blk, 0, stream>>>(x0h, W_hg, KST, EpGates{Zb, RH, lx, b_hg, x0h});
        gemm_nt<<<grid(CB, KST), blk, 0, stream>>>(RH, W_hl, KST, EpLin<2>{Zb, lx, b_hl, x0h, ss, sn, x0h, dtp});

        gemm_nt<<<grid(CB, 2 * KST), blk, 0, stream>>>(x0h, W_hg, KST, EpGates{Zb, RH, lx, b_hg, x0h});
        gemm_nt<<<grid(CB, KST), blk, 0, stream>>>(RH, W_hl, KST, EpLin<3>{Zb, lx, b_hl, x0h, ss, sn, x0h, dtp});
    }

    // 4) y = tanh(state_new @ W_y1^T) @ W_y2^T, chunked; t reuses ws (chunk bufs dead).
    //    CBY*K <= 4*CB*K <= 6*CB*K always fits; B % CBY == 0 for CB in {1024..16384}.
    const int CBY = (4 * CB < Bsz) ? 4 * CB : Bsz;
    float* t = (float*)d_ws;
    for (int c0 = 0; c0 < Bsz; c0 += CBY) {
        gemm_nt<<<grid(CBY, KST), blk, 0, stream>>>(st_new + (size_t)c0 * KST, W_y1, KST, EpTanh{t, KST});
        gemm_nt<<<grid(CBY, KOUT), blk, 0, stream>>>(t, W_y2, KST, EpPlain{y_out + (size_t)c0 * KOUT, KOUT});
    }
}

// Round 7
// 2120.623 us; speedup vs baseline: 3.5012x; 3.5012x over previous
//
#include <hip/hip_runtime.h>
#include <cstdint>
#include <cstddef>

#define DEVI __device__ __forceinline__

namespace {

constexpr int Bsz  = 16384;
constexpr int KIN  = 256;
constexpr int KST  = 1024;
constexpr int KOUT = 256;

typedef __bf16 bf16x8 __attribute__((ext_vector_type(8)));
typedef float  f32x4  __attribute__((ext_vector_type(4)));

DEVI float sigmoidf_(float x) { return 1.0f / (1.0f + expf(-x)); }

DEVI void gload16(const void* gsrc, void* ldst) {
    // async global->LDS, 16B per lane; LDS dest = wave-uniform base + lane*16
    __builtin_amdgcn_global_load_lds((__attribute__((address_space(1))) void*)gsrc,
                                     (__attribute__((address_space(3))) void*)ldst,
                                     16, 0, 0);
}

// ---------------- epilogues (r,c local to the chunk) ----------------
struct EpX0 {                  // x0 = tanh(v + b_in[c]) -> bf16
    __bf16* out; const float* bias;
    DEVI void begin() {}
    DEVI void store(float v, int r, int c) { out[(size_t)r * KST + c] = (__bf16)tanhf(v + bias[c]); }
};
struct EpLx {                  // lx = v (fp32, ldo = 3K)
    float* out;
    DEVI void begin() {}
    DEVI void store(float v, int r, int c) { out[(size_t)r * (3 * KST) + c] = v; }
};
template <class HT>
struct EpGates {               // g = sigmoid(lx + v + b_hg); Z (f32) or RH = bf16(g*h)
    float* Z; __bf16* RH; const float* lx; const float* bhg; const HT* h;
    DEVI void begin() {}
    DEVI void store(float v, int r, int c) {
        const float g = sigmoidf_(lx[(size_t)r * (3 * KST) + c] + v + bhg[c]);
        if (c < KST) {
            Z[(size_t)r * KST + c] = g;
        } else {
            const size_t i = (size_t)r * KST + (c - KST);
            RH[i] = (__bf16)(g * (float)h[i]);
        }
    }
};
// lin = lx[.,2K+c] + v + b_hl; k = Z*(tanh(lin)-h); RK4 update (MEANDT==1).
// STAGE 0..2: acc(f32) accumulates k-combo, hn(bf16) = next h.
// STAGE 3: acc = state + dt*(acc+k)/6 (final state_new, f32) and hn = bf16 copy of it.
template <int STAGE, class HT>
struct EpLin {
    const float* Z; const float* lx; const float* bhl; const HT* h;
    const float* state; float* acc; __bf16* hn; const float* dtp;
    float dtv;
    DEVI void begin() { dtv = *dtp; }
    DEVI void store(float v, int r, int c) {
        const size_t i = (size_t)r * KST + c;
        const float lin = lx[(size_t)r * (3 * KST) + 2 * KST + c] + v + bhl[c];
        const float k = Z[i] * (tanhf(lin) - (float)h[i]);
        if constexpr (STAGE == 0)      { acc[i] = k;            hn[i] = (__bf16)(state[i] + 0.5f * dtv * k); }
        else if constexpr (STAGE == 1) { acc[i] += 2.f * k;     hn[i] = (__bf16)(state[i] + 0.5f * dtv * k); }
        else if constexpr (STAGE == 2) { acc[i] += 2.f * k;     hn[i] = (__bf16)(state[i] + dtv * k); }
        else { const float s = state[i] + dtv * (acc[i] + k) * (1.f / 6.f); acc[i] = s; hn[i] = (__bf16)s; }
    }
};
struct EpT {                   // y1 = tanh(v) -> bf16
    __bf16* out;
    DEVI void begin() {}
    DEVI void store(float v, int r, int c) { out[(size_t)r * KST + c] = (__bf16)tanhf(v); }
};
struct EpY {                   // y = v (fp32 final output)
    float* out;
    DEVI void begin() {}
    DEVI void store(float v, int r, int c) { out[(size_t)r * KOUT + c] = v; }
};

// ---------------- bf16 MFMA NT GEMM (m97 structure) ----------------
// C[M,N] = A[M,K] @ W[N,K]^T. 128x128 tile, BK=32, 4 waves (2x2 of 64x64),
// 16x16x32 MFMA, 4x4 frags/wave, global_load_lds width 16, linear LDS,
// 2 barriers per K-step.
template <class Ep>
__global__ __launch_bounds__(256)
void gemm_bt(const __bf16* __restrict__ A, const __bf16* __restrict__ W,
             const int K, Ep ep)
{
    __shared__ __bf16 As[128 * 32];
    __shared__ __bf16 Bs[128 * 32];
    const int m0 = blockIdx.x * 128;
    const int n0 = blockIdx.y * 128;
    const int t  = threadIdx.x;
    const int l  = t & 63;
    const int w  = t >> 6;          // wave 0..3
    const int wr = w >> 1;          // wave row (0..1) -> 64 rows
    const int wc = w & 1;           // wave col (0..1) -> 64 cols
    const int fr = l & 15;          // fragment row/col index
    const int fq = l >> 4;          // k-quad 0..3 (8 bf16 each)
    const int srow = t >> 2;        // staging row 0..63
    const int sk   = (t & 3) << 3;  // staging k elem 0,8,16,24

    const __bf16* Ap0 = A + (size_t)(m0 + srow) * K + sk;
    const __bf16* Ap1 = Ap0 + (size_t)64 * K;
    const __bf16* Bp0 = W + (size_t)(n0 + srow) * K + sk;
    const __bf16* Bp1 = Bp0 + (size_t)64 * K;
    __bf16* la0 = &As[t * 8];
    __bf16* la1 = &As[2048 + t * 8];
    __bf16* lb0 = &Bs[t * 8];
    __bf16* lb1 = &Bs[2048 + t * 8];

    f32x4 acc[4][4];
#pragma unroll
    for (int i = 0; i < 4; ++i)
#pragma unroll
        for (int j = 0; j < 4; ++j) acc[i][j] = (f32x4){0.f, 0.f, 0.f, 0.f};

    for (int k0 = 0; k0 < K; k0 += 32) {
        gload16(Ap0 + k0, la0);
        gload16(Ap1 + k0, la1);
        gload16(Bp0 + k0, lb0);
        gload16(Bp1 + k0, lb1);
        __syncthreads();            // drains vmcnt -> LDS tile ready
        bf16x8 av[4], bv[4];
#pragma unroll
        for (int mi = 0; mi < 4; ++mi)
            av[mi] = *(const bf16x8*)&As[(wr * 64 + mi * 16 + fr) * 32 + fq * 8];
#pragma unroll
        for (int ni = 0; ni < 4; ++ni)
            bv[ni] = *(const bf16x8*)&Bs[(wc * 64 + ni * 16 + fr) * 32 + fq * 8];
#pragma unroll
        for (int mi = 0; mi < 4; ++mi)
#pragma unroll
            for (int ni = 0; ni < 4; ++ni)
                acc[mi][ni] = __builtin_amdgcn_mfma_f32_16x16x32_bf16(av[mi], bv[ni], acc[mi][ni], 0, 0, 0);
        __syncthreads();            // compute done before next tile overwrite
    }

    ep.begin();
#pragma unroll
    for (int mi = 0; mi < 4; ++mi)
#pragma unroll
        for (int ni = 0; ni < 4; ++ni)
#pragma unroll
            for (int j = 0; j < 4; ++j)
                ep.store(acc[mi][ni][j],
                         m0 + wr * 64 + mi * 16 + fq * 4 + j,
                         n0 + wc * 64 + ni * 16 + fr);
}

// ---------------- f32 -> bf16 conversion (vectorized, grid-stride) ----------------
__global__ __launch_bounds__(256)
void cvt_bf16(const float* __restrict__ s, __bf16* __restrict__ d, int n8)
{
    for (int i = blockIdx.x * blockDim.x + threadIdx.x; i < n8; i += gridDim.x * blockDim.x) {
        const float4 a = ((const float4*)s)[2 * i];
        const float4 b = ((const float4*)s)[2 * i + 1];
        bf16x8 v;
        v[0] = (__bf16)a.x; v[1] = (__bf16)a.y; v[2] = (__bf16)a.z; v[3] = (__bf16)a.w;
        v[4] = (__bf16)b.x; v[5] = (__bf16)b.y; v[6] = (__bf16)b.z; v[7] = (__bf16)b.w;
        ((bf16x8*)d)[i] = v;
    }
}

} // namespace

extern "C" void kernel_launch(void* const* d_in, const int* in_sizes, int n_in,
                              void* d_out, int out_size, void* d_ws, size_t ws_size,
                              hipStream_t stream)
{
    (void)in_sizes; (void)n_in; (void)out_size;

    const float* x     = (const float*)d_in[0];
    const float* state = (const float*)d_in[1];
    const float* dtp   = (const float*)d_in[2];
    const float* W_in  = (const float*)d_in[3];
    const float* b_in  = (const float*)d_in[4];
    const float* W_lx  = (const float*)d_in[5];
    const float* W_hg  = (const float*)d_in[6];
    const float* b_hg  = (const float*)d_in[7];
    const float* W_hl  = (const float*)d_in[8];
    const float* b_hl  = (const float*)d_in[9];
    const float* W_y1  = (const float*)d_in[10];
    const float* W_y2  = (const float*)d_in[11];

    float* y_out  = (float*)d_out;                    // [B, KOUT] f32
    float* st_new = y_out + (size_t)Bsz * KOUT;       // [B, KST] f32; doubles as RK4 acc

    // ---- workspace layout ----
    // fixed: x_bf | state_bf | stn_bf | 6 bf16 weight buffers  (~91 MB)
    // chunk: lx (12 CB*K B) | Z (4) | h_bf (2) | RH (2)  = 20*CB*K bytes
    const size_t nWin = (size_t)KST * KIN, nWlx = (size_t)3 * KST * KST,
                 nWhg = (size_t)2 * KST * KST, nWhl = (size_t)KST * KST,
                 nWy1 = (size_t)KST * KST, nWy2 = (size_t)KOUT * KST;
    const size_t fixedB = ((size_t)Bsz * KIN + 2 * (size_t)Bsz * KST
                           + nWin + nWlx + nWhg + nWhl + nWy1 + nWy2) * 2;

    int CB = 1024;
    while (CB < Bsz && fixedB + (size_t)(2 * CB) * KST * 20 <= ws_size) CB <<= 1;
    if (fixedB + (size_t)CB * KST * 20 > ws_size) return;

    uint8_t* p = (uint8_t*)d_ws;
    __bf16* x_bf  = (__bf16*)p; p += (size_t)Bsz * KIN * 2;
    __bf16* st_bf = (__bf16*)p; p += (size_t)Bsz * KST * 2;
    __bf16* snb   = (__bf16*)p; p += (size_t)Bsz * KST * 2;
    __bf16* Wb_in = (__bf16*)p; p += nWin * 2;
    __bf16* Wb_lx = (__bf16*)p; p += nWlx * 2;
    __bf16* Wb_hg = (__bf16*)p; p += nWhg * 2;
    __bf16* Wb_hl = (__bf16*)p; p += nWhl * 2;
    __bf16* Wb_y1 = (__bf16*)p; p += nWy1 * 2;
    __bf16* Wb_y2 = (__bf16*)p; p += nWy2 * 2;
    float*  lx    = (float*)p;  p += (size_t)CB * 3 * KST * 4;
    float*  Zb    = (float*)p;  p += (size_t)CB * KST * 4;
    __bf16* h_bf  = (__bf16*)p; p += (size_t)CB * KST * 2;
    __bf16* RH    = (__bf16*)p;
    __bf16* t_bf  = (__bf16*)lx;   // y-phase scratch aliases lx (dead by then)

    const dim3 blk(256);
    auto cg = [](size_t n) { return dim3((unsigned)((n / 8 + 255) / 256 > 2048 ? 2048 : (n / 8 + 255) / 256)); };
    auto g  = [](int M, int N) { return dim3((unsigned)(M / 128), (unsigned)(N / 128)); };

    // ---- one-time f32 -> bf16 conversions ----
    cvt_bf16<<<cg((size_t)Bsz * KIN), blk, 0, stream>>>(x, x_bf, (int)((size_t)Bsz * KIN / 8));
    cvt_bf16<<<cg((size_t)Bsz * KST), blk, 0, stream>>>(state, st_bf, (int)((size_t)Bsz * KST / 8));
    cvt_bf16<<<cg(nWin), blk, 0, stream>>>(W_in, Wb_in, (int)(nWin / 8));
    cvt_bf16<<<cg(nWlx), blk, 0, stream>>>(W_lx, Wb_lx, (int)(nWlx / 8));
    cvt_bf16<<<cg(nWhg), blk, 0, stream>>>(W_hg, Wb_hg, (int)(nWhg / 8));
    cvt_bf16<<<cg(nWhl), blk, 0, stream>>>(W_hl, Wb_hl, (int)(nWhl / 8));
    cvt_bf16<<<cg(nWy1), blk, 0, stream>>>(W_y1, Wb_y1, (int)(nWy1 / 8));
    cvt_bf16<<<cg(nWy2), blk, 0, stream>>>(W_y2, Wb_y2, (int)(nWy2 / 8));

    for (int c0 = 0; c0 < Bsz; c0 += CB) {
        const __bf16* xs  = x_bf + (size_t)c0 * KIN;
        const __bf16* ssb = st_bf + (size_t)c0 * KST;
        const float*  ss  = state + (size_t)c0 * KST;
        float*  sn   = st_new + (size_t)c0 * KST;
        __bf16* snbs = snb + (size_t)c0 * KST;

        // x0 = tanh(x W_in^T + b_in)  [bf16 -> h_bf]
        gemm_bt<<<g(CB, KST), blk, 0, stream>>>(xs, Wb_in, KIN, EpX0{h_bf, b_in});
        // lx = x0 W_lx^T  [f32]
        gemm_bt<<<g(CB, 3 * KST), blk, 0, stream>>>(h_bf, Wb_lx, KST, EpLx{lx});

        // RK4 stage 0 (h = state)
        gemm_bt<<<g(CB, 2 * KST), blk, 0, stream>>>(ssb, Wb_hg, KST, EpGates<float>{Zb, RH, lx, b_hg, ss});
        gemm_bt<<<g(CB, KST), blk, 0, stream>>>(RH, Wb_hl, KST, EpLin<0, float>{Zb, lx, b_hl, ss, ss, sn, h_bf, dtp});
        // stages 1..3 (h = h_bf)
        gemm_bt<<<g(CB, 2 * KST), blk, 0, stream>>>(h_bf, Wb_hg, KST, EpGates<__bf16>{Zb, RH, lx, b_hg, h_bf});
        gemm_bt<<<g(CB, KST), blk, 0, stream>>>(RH, Wb_hl, KST, EpLin<1, __bf16>{Zb, lx, b_hl, h_bf, ss, sn, h_bf, dtp});
        gemm_bt<<<g(CB, 2 * KST), blk, 0, stream>>>(h_bf, Wb_hg, KST, EpGates<__bf16>{Zb, RH, lx, b_hg, h_bf});
        gemm_bt<<<g(CB, KST), blk, 0, stream>>>(RH, Wb_hl, KST, EpLin<2, __bf16>{Zb, lx, b_hl, h_bf, ss, sn, h_bf, dtp});
        gemm_bt<<<g(CB, 2 * KST), blk, 0, stream>>>(h_bf, Wb_hg, KST, EpGates<__bf16>{Zb, RH, lx, b_hg, h_bf});
        gemm_bt<<<g(CB, KST), blk, 0, stream>>>(RH, Wb_hl, KST, EpLin<3, __bf16>{Zb, lx, b_hl, h_bf, ss, sn, snbs, dtp});
    }

    // y = tanh(state_new W_y1^T) W_y2^T ; t_bf reuses chunk scratch
    const int CBY = (4 * CB < Bsz) ? 4 * CB : Bsz;
    for (int c0 = 0; c0 < Bsz; c0 += CBY) {
        gemm_bt<<<g(CBY, KST), blk, 0, stream>>>(snb + (size_t)c0 * KST, Wb_y1, KST, EpT{t_bf});
        gemm_bt<<<g(CBY, KOUT), blk, 0, stream>>>(t_bf, Wb_y2, KST, EpY{y_out + (size_t)c0 * KOUT});
    }
}